// Round 1
// baseline (578.600 us; speedup 1.0000x reference)
//
#include <hip/hip_runtime.h>
#include <math.h>

#define N_NODES 50000
#define E_EDGES 500000
#define P_PAIRS 200000

// ---------------- CSR build ----------------

__global__ void count_deg_k(const int* __restrict__ dst, int* __restrict__ deg) {
    int e = blockIdx.x * blockDim.x + threadIdx.x;
    if (e < E_EDGES) atomicAdd(&deg[dst[e]], 1);
}

__global__ __launch_bounds__(1024) void scanA_k(const int* __restrict__ deg,
                                                int* __restrict__ rowptr,
                                                int* __restrict__ blockSums) {
    __shared__ int buf[1024];
    int t = threadIdx.x;
    int i = blockIdx.x * 1024 + t;
    int v = (i < N_NODES) ? deg[i] : 0;
    buf[t] = v;
    __syncthreads();
    for (int off = 1; off < 1024; off <<= 1) {
        int xv = (t >= off) ? buf[t - off] : 0;
        __syncthreads();
        buf[t] += xv;
        __syncthreads();
    }
    if (i < N_NODES) rowptr[i] = buf[t] - v;   // block-local exclusive
    if (t == 1023) blockSums[blockIdx.x] = buf[1023];
}

__global__ void scanB_k(const int* __restrict__ blockSums, int* __restrict__ blockOffs,
                        int* __restrict__ rowptr, int nblk) {
    if (threadIdx.x == 0 && blockIdx.x == 0) {
        int run = 0;
        for (int b = 0; b < nblk; ++b) { blockOffs[b] = run; run += blockSums[b]; }
        rowptr[N_NODES] = run;   // == E_EDGES
    }
}

__global__ void scanC_k(int* __restrict__ rowptr, const int* __restrict__ blockOffs) {
    int i = blockIdx.x * blockDim.x + threadIdx.x;
    if (i < N_NODES) rowptr[i] += blockOffs[i >> 10];
}

__global__ void fill_csr_k(const int* __restrict__ src, const int* __restrict__ dst,
                           const int* __restrict__ rowptr, int* __restrict__ fil,
                           int* __restrict__ csr) {
    int e = blockIdx.x * blockDim.x + threadIdx.x;
    if (e < E_EDGES) {
        int d = dst[e];
        int pos = rowptr[d] + atomicAdd(&fil[d], 1);
        csr[pos] = src[e];
    }
}

// ---------------- weight prep: k-major transposed concat weights ----------------
// WT[k*128+o]; k<128 -> Wl[o][k] (agg part), k>=128 -> Wr[o][k-128] (self part).
// W3T[k*128+o] = W3[o][k] (k in 0..255).

__global__ void prep_w_k(const float* __restrict__ Wl1, const float* __restrict__ Wr1,
                         const float* __restrict__ Wl2, const float* __restrict__ Wr2,
                         const float* __restrict__ W3,
                         float* __restrict__ WT1, float* __restrict__ WT2,
                         float* __restrict__ W3T) {
    int i = blockIdx.x * blockDim.x + threadIdx.x;
    if (i < 256 * 128) {
        int k = i >> 7, o = i & 127;
        WT1[i] = (k < 128) ? Wl1[o * 128 + k] : Wr1[o * 128 + (k - 128)];
        WT2[i] = (k < 128) ? Wl2[o * 128 + k] : Wr2[o * 128 + (k - 128)];
        W3T[i] = W3[o * 256 + k];
    }
}

// ---------------- segment-mean aggregation via CSR gather ----------------
// 8 nodes per 256-thread block; 32 lanes x float4 cover the 128-f row.

__global__ __launch_bounds__(256) void aggregate_k(const float* __restrict__ feat,
                                                   const int* __restrict__ rowptr,
                                                   const int* __restrict__ csr,
                                                   float* __restrict__ agg) {
    int n = blockIdx.x * 8 + (threadIdx.x >> 5);
    if (n >= N_NODES) return;
    int l = threadIdx.x & 31;
    int beg = rowptr[n], end = rowptr[n + 1];
    float4 s = make_float4(0.f, 0.f, 0.f, 0.f);
    for (int j = beg; j < end; ++j) {
        int sn = csr[j];
        float4 v = *(const float4*)(feat + (size_t)sn * 128 + l * 4);
        s.x += v.x; s.y += v.y; s.z += v.z; s.w += v.w;
    }
    float inv = 1.0f / fmaxf((float)(end - beg), 1.0f);
    s.x *= inv; s.y *= inv; s.z *= inv; s.w *= inv;
    *(float4*)(agg + (size_t)n * 128 + l * 4) = s;
}

// ---------------- fused SAGE layer GEMM: out = relu([agg|feat] @ WT + b) ----------------
// Tile: 32 nodes x 128 outputs, 256 threads, each thread 4 nodes x 4 outputs.

__global__ __launch_bounds__(256) void layer_gemm_k(const float* __restrict__ agg,
                                                    const float* __restrict__ feat,
                                                    const float* __restrict__ WT,
                                                    const float* __restrict__ bias,
                                                    float* __restrict__ out) {
    __shared__ float sAct[32 * 256];
    int t = threadIdx.x;
    int tileBase = blockIdx.x * 32;

    // stage 32x256 activation tile: [agg row | feat row]
    #pragma unroll
    for (int r = 0; r < 8; ++r) {
        int q = r * 256 + t;         // float4 index 0..2047
        int m = q >> 6;
        int k4 = (q & 63) << 2;
        int node = tileBase + m;
        if (node >= N_NODES) node = N_NODES - 1;
        const float* srcp = (k4 < 128) ? (agg + (size_t)node * 128 + k4)
                                       : (feat + (size_t)node * 128 + (k4 - 128));
        *(float4*)(sAct + m * 256 + k4) = *(const float4*)srcp;
    }
    __syncthreads();

    int om = t & 31, mm = t >> 5;
    int o = om << 2;
    float4 bv = *(const float4*)(bias + o);
    float acc[4][4];
    #pragma unroll
    for (int i = 0; i < 4; ++i) { acc[i][0] = bv.x; acc[i][1] = bv.y; acc[i][2] = bv.z; acc[i][3] = bv.w; }

    const float* actb = sAct + mm * 4 * 256;
    #pragma unroll 2
    for (int k = 0; k < 256; k += 4) {
        float4 a4[4];
        #pragma unroll
        for (int i = 0; i < 4; ++i) a4[i] = *(const float4*)(actb + i * 256 + k);
        #pragma unroll
        for (int kk = 0; kk < 4; ++kk) {
            float4 w = *(const float4*)(WT + (k + kk) * 128 + o);
            #pragma unroll
            for (int i = 0; i < 4; ++i) {
                float a = ((const float*)&a4[i])[kk];
                acc[i][0] += a * w.x; acc[i][1] += a * w.y;
                acc[i][2] += a * w.z; acc[i][3] += a * w.w;
            }
        }
    }

    #pragma unroll
    for (int i = 0; i < 4; ++i) {
        int node = tileBase + mm * 4 + i;
        if (node < N_NODES) {
            float4 ov;
            ov.x = fmaxf(acc[i][0], 0.f); ov.y = fmaxf(acc[i][1], 0.f);
            ov.z = fmaxf(acc[i][2], 0.f); ov.w = fmaxf(acc[i][3], 0.f);
            *(float4*)(out + (size_t)node * 128 + o) = ov;
        }
    }
}

// ---------------- pair MLP: sigmoid(relu([h2[a]|h2[b]] @ W3T + b3) . W4 + b4) ----------------
// Tile: 32 pairs x 128 hidden, 256 threads, 4x4 per thread, shuffle-reduce over o.

__global__ __launch_bounds__(256) void pair_mlp_k(const float* __restrict__ h2,
                                                  const int* __restrict__ pairs,
                                                  const float* __restrict__ W3T,
                                                  const float* __restrict__ b3,
                                                  const float* __restrict__ W4,
                                                  const float* __restrict__ b4,
                                                  float* __restrict__ out) {
    __shared__ float sAct[32 * 256];
    __shared__ int sPair[64];
    int t = threadIdx.x;
    int tileBase = blockIdx.x * 32;
    if (t < 64) sPair[t] = pairs[tileBase * 2 + t];
    __syncthreads();

    #pragma unroll
    for (int r = 0; r < 8; ++r) {
        int q = r * 256 + t;
        int m = q >> 6;
        int k4 = (q & 63) << 2;
        int node = (k4 < 128) ? sPair[2 * m] : sPair[2 * m + 1];
        *(float4*)(sAct + m * 256 + k4) = *(const float4*)(h2 + (size_t)node * 128 + (k4 & 127));
    }
    __syncthreads();

    int om = t & 31, mm = t >> 5;
    int o = om << 2;
    float4 bv = *(const float4*)(b3 + o);
    float4 w4 = *(const float4*)(W4 + o);
    float acc[4][4];
    #pragma unroll
    for (int i = 0; i < 4; ++i) { acc[i][0] = bv.x; acc[i][1] = bv.y; acc[i][2] = bv.z; acc[i][3] = bv.w; }

    const float* actb = sAct + mm * 4 * 256;
    #pragma unroll 2
    for (int k = 0; k < 256; k += 4) {
        float4 a4[4];
        #pragma unroll
        for (int i = 0; i < 4; ++i) a4[i] = *(const float4*)(actb + i * 256 + k);
        #pragma unroll
        for (int kk = 0; kk < 4; ++kk) {
            float4 w = *(const float4*)(W3T + (k + kk) * 128 + o);
            #pragma unroll
            for (int i = 0; i < 4; ++i) {
                float a = ((const float*)&a4[i])[kk];
                acc[i][0] += a * w.x; acc[i][1] += a * w.y;
                acc[i][2] += a * w.z; acc[i][3] += a * w.w;
            }
        }
    }

    float b4s = b4[0];
    #pragma unroll
    for (int i = 0; i < 4; ++i) {
        float p = fmaxf(acc[i][0], 0.f) * w4.x + fmaxf(acc[i][1], 0.f) * w4.y
                + fmaxf(acc[i][2], 0.f) * w4.z + fmaxf(acc[i][3], 0.f) * w4.w;
        #pragma unroll
        for (int s = 16; s > 0; s >>= 1) p += __shfl_down(p, s, 32);
        if (om == 0) {
            int pi = tileBase + mm * 4 + i;
            out[pi] = 1.0f / (1.0f + expf(-(p + b4s)));
        }
    }
}

// ---------------- launch ----------------

extern "C" void kernel_launch(void* const* d_in, const int* in_sizes, int n_in,
                              void* d_out, int out_size, void* d_ws, size_t ws_size,
                              hipStream_t stream) {
    const float* x   = (const float*)d_in[0];
    const int*   ei  = (const int*)d_in[1];
    const int*   prs = (const int*)d_in[2];
    const float* Wl1 = (const float*)d_in[3];
    const float* Wr1 = (const float*)d_in[4];
    const float* b1  = (const float*)d_in[5];
    const float* Wl2 = (const float*)d_in[6];
    const float* Wr2 = (const float*)d_in[7];
    const float* b2  = (const float*)d_in[8];
    const float* W3  = (const float*)d_in[9];
    const float* b3  = (const float*)d_in[10];
    const float* W4  = (const float*)d_in[11];
    const float* b4  = (const float*)d_in[12];
    float* out = (float*)d_out;

    const int* srcv = ei;            // edge_index[0]
    const int* dstv = ei + E_EDGES;  // edge_index[1]

    char* ws = (char*)d_ws;
    size_t off = 0;
    auto alloc = [&](size_t bytes) -> void* {
        void* p = ws + off;
        off = (off + bytes + 255) & ~(size_t)255;
        return p;
    };
    int*   deg    = (int*)alloc(sizeof(int) * N_NODES);
    int*   fil    = (int*)alloc(sizeof(int) * N_NODES);
    int*   rowptr = (int*)alloc(sizeof(int) * (N_NODES + 1));
    int*   bsum   = (int*)alloc(sizeof(int) * 64);
    int*   boff   = (int*)alloc(sizeof(int) * 64);
    int*   csr    = (int*)alloc(sizeof(int) * E_EDGES);
    float* WT1    = (float*)alloc(sizeof(float) * 256 * 128);
    float* WT2    = (float*)alloc(sizeof(float) * 256 * 128);
    float* W3T    = (float*)alloc(sizeof(float) * 256 * 128);
    float* agg    = (float*)alloc(sizeof(float) * (size_t)N_NODES * 128);
    float* h1     = (float*)alloc(sizeof(float) * (size_t)N_NODES * 128);
    float* h2     = (float*)alloc(sizeof(float) * (size_t)N_NODES * 128);
    (void)ws_size; (void)in_sizes; (void)n_in; (void)out_size;

    hipMemsetAsync(deg, 0, sizeof(int) * N_NODES, stream);
    hipMemsetAsync(fil, 0, sizeof(int) * N_NODES, stream);

    const int nScanBlk = (N_NODES + 1023) / 1024;
    count_deg_k<<<(E_EDGES + 255) / 256, 256, 0, stream>>>(dstv, deg);
    scanA_k<<<nScanBlk, 1024, 0, stream>>>(deg, rowptr, bsum);
    scanB_k<<<1, 1, 0, stream>>>(bsum, boff, rowptr, nScanBlk);
    scanC_k<<<(N_NODES + 255) / 256, 256, 0, stream>>>(rowptr, boff);
    fill_csr_k<<<(E_EDGES + 255) / 256, 256, 0, stream>>>(srcv, dstv, rowptr, fil, csr);
    prep_w_k<<<(256 * 128 + 255) / 256, 256, 0, stream>>>(Wl1, Wr1, Wl2, Wr2, W3, WT1, WT2, W3T);

    // layer 1
    aggregate_k<<<(N_NODES + 7) / 8, 256, 0, stream>>>(x, rowptr, csr, agg);
    layer_gemm_k<<<(N_NODES + 31) / 32, 256, 0, stream>>>(agg, x, WT1, b1, h1);
    // layer 2
    aggregate_k<<<(N_NODES + 7) / 8, 256, 0, stream>>>(h1, rowptr, csr, agg);
    layer_gemm_k<<<(N_NODES + 31) / 32, 256, 0, stream>>>(agg, h1, WT2, b2, h2);
    // pair scoring
    pair_mlp_k<<<P_PAIRS / 32, 256, 0, stream>>>(h2, prs, W3T, b3, W4, b4, out);
}

// Round 2
// 307.626 us; speedup vs baseline: 1.8809x; 1.8809x over previous
//
#include <hip/hip_runtime.h>
#include <math.h>

#define N_NODES 50000
#define E_EDGES 500000
#define P_PAIRS 200000

typedef __bf16  bf16x8 __attribute__((ext_vector_type(8)));
typedef float   f32x4  __attribute__((ext_vector_type(4)));

// ---------------- CSR build ----------------

__global__ void count_deg_k(const int* __restrict__ dst, int* __restrict__ deg) {
    int e = blockIdx.x * blockDim.x + threadIdx.x;
    if (e < E_EDGES) atomicAdd(&deg[dst[e]], 1);
}

__global__ __launch_bounds__(1024) void scanA_k(const int* __restrict__ deg,
                                                int* __restrict__ rowptr,
                                                int* __restrict__ blockSums) {
    __shared__ int buf[1024];
    int t = threadIdx.x;
    int i = blockIdx.x * 1024 + t;
    int v = (i < N_NODES) ? deg[i] : 0;
    buf[t] = v;
    __syncthreads();
    for (int off = 1; off < 1024; off <<= 1) {
        int xv = (t >= off) ? buf[t - off] : 0;
        __syncthreads();
        buf[t] += xv;
        __syncthreads();
    }
    if (i < N_NODES) rowptr[i] = buf[t] - v;
    if (t == 1023) blockSums[blockIdx.x] = buf[1023];
}

__global__ void scanB_k(const int* __restrict__ blockSums, int* __restrict__ blockOffs,
                        int* __restrict__ rowptr, int nblk) {
    if (threadIdx.x == 0 && blockIdx.x == 0) {
        int run = 0;
        for (int b = 0; b < nblk; ++b) { blockOffs[b] = run; run += blockSums[b]; }
        rowptr[N_NODES] = run;
    }
}

__global__ void scanC_k(int* __restrict__ rowptr, const int* __restrict__ blockOffs) {
    int i = blockIdx.x * blockDim.x + threadIdx.x;
    if (i < N_NODES) rowptr[i] += blockOffs[i >> 10];
}

__global__ void fill_csr_k(const int* __restrict__ src, const int* __restrict__ dst,
                           const int* __restrict__ rowptr, int* __restrict__ fil,
                           int* __restrict__ csr) {
    int e = blockIdx.x * blockDim.x + threadIdx.x;
    if (e < E_EDGES) {
        int d = dst[e];
        int pos = rowptr[d] + atomicAdd(&fil[d], 1);
        csr[pos] = src[e];
    }
}

// ---------------- fp32 -> bf16 feature conversion ----------------

__global__ __launch_bounds__(256) void conv_x_k(const float* __restrict__ x,
                                                __bf16* __restrict__ xb) {
    int i = blockIdx.x * blockDim.x + threadIdx.x;   // float4 index
    if (i < N_NODES * 128 / 4) {
        float4 v = ((const float4*)x)[i];
        __bf16* o = xb + i * 4;
        o[0] = (__bf16)v.x; o[1] = (__bf16)v.y; o[2] = (__bf16)v.z; o[3] = (__bf16)v.w;
    }
}

// ---------------- weight pack: fragment-major bf16 ----------------
// Pack layout: [kt(8)][nt(8)][lane(64)][j(8)] ; B[k][n] with
//   n = nt*16 + (lane&15), k = kt*32 + (lane>>4)*8 + j.
// Layer weights: k<128 -> Wl[n][k] (agg), k>=128 -> Wr[n][k-128] (self).
// W3: B[k][n] = W3[n*256 + k].

__global__ __launch_bounds__(256) void prep_wpack_k(
        const float* __restrict__ Wl1, const float* __restrict__ Wr1,
        const float* __restrict__ Wl2, const float* __restrict__ Wr2,
        const float* __restrict__ W3,
        __bf16* __restrict__ P1, __bf16* __restrict__ P2, __bf16* __restrict__ P3) {
    int i = blockIdx.x * blockDim.x + threadIdx.x;
    if (i < 256 * 128) {
        int kt = i >> 12;
        int nt = (i >> 9) & 7;
        int lane = (i >> 3) & 63;
        int j = i & 7;
        int n = nt * 16 + (lane & 15);
        int k = kt * 32 + (lane >> 4) * 8 + j;
        float v1 = (k < 128) ? Wl1[n * 128 + k] : Wr1[n * 128 + (k - 128)];
        float v2 = (k < 128) ? Wl2[n * 128 + k] : Wr2[n * 128 + (k - 128)];
        P1[i] = (__bf16)v1;
        P2[i] = (__bf16)v2;
        P3[i] = (__bf16)W3[n * 256 + k];
    }
}

// ---------------- segment-mean aggregation (bf16 in, bf16 out) ----------------
// 16 lanes per node, each lane covers 8 contiguous bf16 (16 B).

__global__ __launch_bounds__(256) void aggregate_bf_k(const __bf16* __restrict__ feat,
                                                      const int* __restrict__ rowptr,
                                                      const int* __restrict__ csr,
                                                      __bf16* __restrict__ agg) {
    int n = blockIdx.x * 16 + (threadIdx.x >> 4);
    if (n >= N_NODES) return;
    int l = threadIdx.x & 15;
    int beg = rowptr[n], end = rowptr[n + 1];
    float s[8];
    #pragma unroll
    for (int e = 0; e < 8; ++e) s[e] = 0.f;
    for (int j = beg; j < end; ++j) {
        int sn = csr[j];
        bf16x8 v = *(const bf16x8*)(feat + (size_t)sn * 128 + l * 8);
        #pragma unroll
        for (int e = 0; e < 8; ++e) s[e] += (float)v[e];
    }
    float inv = 1.0f / fmaxf((float)(end - beg), 1.0f);
    bf16x8 o;
    #pragma unroll
    for (int e = 0; e < 8; ++e) o[e] = (__bf16)(s[e] * inv);
    *(bf16x8*)(agg + (size_t)n * 128 + l * 8) = o;
}

// ---------------- SAGE layer: out = relu([agg|feat] @ B + bias), bf16 MFMA ----------------
// Block = 256 threads = 4 waves; wave handles 32 rows (2 groups of 16); N=128 outputs.

__global__ __launch_bounds__(256) void layer_mfma_k(const __bf16* __restrict__ agg,
                                                    const __bf16* __restrict__ feat,
                                                    const __bf16* __restrict__ wpack,
                                                    const float* __restrict__ bias,
                                                    __bf16* __restrict__ out) {
    int wave = threadIdx.x >> 6;
    int lane = threadIdx.x & 63;
    int m = lane & 15, quad = lane >> 4;
    int rbase = blockIdx.x * 128 + wave * 32;

    int r0 = rbase + m;       if (r0 > N_NODES - 1) r0 = N_NODES - 1;
    int r1 = rbase + 16 + m;  if (r1 > N_NODES - 1) r1 = N_NODES - 1;

    f32x4 acc[2][8];
    #pragma unroll
    for (int g = 0; g < 2; ++g)
        #pragma unroll
        for (int nt = 0; nt < 8; ++nt) acc[g][nt] = (f32x4)0.f;

    #pragma unroll
    for (int kt = 0; kt < 8; ++kt) {
        const __bf16* src = (kt < 4) ? agg : feat;
        int ko = (kt & 3) * 32 + quad * 8;
        bf16x8 a0 = *(const bf16x8*)(src + (size_t)r0 * 128 + ko);
        bf16x8 a1 = *(const bf16x8*)(src + (size_t)r1 * 128 + ko);
        const __bf16* wb = wpack + (size_t)kt * 4096 + lane * 8;
        #pragma unroll
        for (int nt = 0; nt < 8; ++nt) {
            bf16x8 b = *(const bf16x8*)(wb + nt * 512);
            acc[0][nt] = __builtin_amdgcn_mfma_f32_16x16x32_bf16(a0, b, acc[0][nt], 0, 0, 0);
            acc[1][nt] = __builtin_amdgcn_mfma_f32_16x16x32_bf16(a1, b, acc[1][nt], 0, 0, 0);
        }
    }

    int col = lane & 15;
    #pragma unroll
    for (int g = 0; g < 2; ++g)
        #pragma unroll
        for (int r = 0; r < 4; ++r) {
            int row = rbase + g * 16 + quad * 4 + r;
            if (row < N_NODES) {
                #pragma unroll
                for (int nt = 0; nt < 8; ++nt) {
                    float v = acc[g][nt][r] + bias[nt * 16 + col];
                    out[(size_t)row * 128 + nt * 16 + col] = (__bf16)fmaxf(v, 0.f);
                }
            }
        }
}

// ---------------- pair MLP: sigmoid(relu([h2[a]|h2[b]] @ W3T + b3) . W4 + b4) ----------------

__global__ __launch_bounds__(256) void pair_mfma_k(const __bf16* __restrict__ h2,
                                                   const int* __restrict__ pairs,
                                                   const __bf16* __restrict__ wpack,
                                                   const float* __restrict__ b3,
                                                   const float* __restrict__ W4,
                                                   const float* __restrict__ b4,
                                                   float* __restrict__ out) {
    int wave = threadIdx.x >> 6;
    int lane = threadIdx.x & 63;
    int m = lane & 15, quad = lane >> 4;
    int pbase = blockIdx.x * 128 + wave * 32;

    int p0 = pbase + m;       if (p0 > P_PAIRS - 1) p0 = P_PAIRS - 1;
    int p1 = pbase + 16 + m;  if (p1 > P_PAIRS - 1) p1 = P_PAIRS - 1;
    int2 pr0 = ((const int2*)pairs)[p0];
    int2 pr1 = ((const int2*)pairs)[p1];

    f32x4 acc[2][8];
    #pragma unroll
    for (int g = 0; g < 2; ++g)
        #pragma unroll
        for (int nt = 0; nt < 8; ++nt) acc[g][nt] = (f32x4)0.f;

    #pragma unroll
    for (int kt = 0; kt < 8; ++kt) {
        int n0 = (kt < 4) ? pr0.x : pr0.y;
        int n1 = (kt < 4) ? pr1.x : pr1.y;
        int ko = (kt & 3) * 32 + quad * 8;
        bf16x8 a0 = *(const bf16x8*)(h2 + (size_t)n0 * 128 + ko);
        bf16x8 a1 = *(const bf16x8*)(h2 + (size_t)n1 * 128 + ko);
        const __bf16* wb = wpack + (size_t)kt * 4096 + lane * 8;
        #pragma unroll
        for (int nt = 0; nt < 8; ++nt) {
            bf16x8 b = *(const bf16x8*)(wb + nt * 512);
            acc[0][nt] = __builtin_amdgcn_mfma_f32_16x16x32_bf16(a0, b, acc[0][nt], 0, 0, 0);
            acc[1][nt] = __builtin_amdgcn_mfma_f32_16x16x32_bf16(a1, b, acc[1][nt], 0, 0, 0);
        }
    }

    int col = lane & 15;
    float w4v[8], b3v[8];
    #pragma unroll
    for (int nt = 0; nt < 8; ++nt) {
        w4v[nt] = W4[nt * 16 + col];
        b3v[nt] = b3[nt * 16 + col];
    }
    float b4s = b4[0];

    #pragma unroll
    for (int g = 0; g < 2; ++g)
        #pragma unroll
        for (int r = 0; r < 4; ++r) {
            float part = 0.f;
            #pragma unroll
            for (int nt = 0; nt < 8; ++nt)
                part += fmaxf(acc[g][nt][r] + b3v[nt], 0.f) * w4v[nt];
            #pragma unroll
            for (int s = 1; s < 16; s <<= 1) part += __shfl_xor(part, s, 64);
            if (col == 0) {
                int pi = pbase + g * 16 + quad * 4 + r;
                if (pi < P_PAIRS)
                    out[pi] = 1.0f / (1.0f + expf(-(part + b4s)));
            }
        }
}

// ---------------- launch ----------------

extern "C" void kernel_launch(void* const* d_in, const int* in_sizes, int n_in,
                              void* d_out, int out_size, void* d_ws, size_t ws_size,
                              hipStream_t stream) {
    const float* x   = (const float*)d_in[0];
    const int*   ei  = (const int*)d_in[1];
    const int*   prs = (const int*)d_in[2];
    const float* Wl1 = (const float*)d_in[3];
    const float* Wr1 = (const float*)d_in[4];
    const float* b1  = (const float*)d_in[5];
    const float* Wl2 = (const float*)d_in[6];
    const float* Wr2 = (const float*)d_in[7];
    const float* b2  = (const float*)d_in[8];
    const float* W3  = (const float*)d_in[9];
    const float* b3  = (const float*)d_in[10];
    const float* W4  = (const float*)d_in[11];
    const float* b4  = (const float*)d_in[12];
    float* out = (float*)d_out;

    const int* srcv = ei;
    const int* dstv = ei + E_EDGES;

    char* ws = (char*)d_ws;
    size_t off = 0;
    auto alloc = [&](size_t bytes) -> void* {
        void* p = ws + off;
        off = (off + bytes + 255) & ~(size_t)255;
        return p;
    };
    int*    deg    = (int*)alloc(sizeof(int) * N_NODES);
    int*    fil    = (int*)alloc(sizeof(int) * N_NODES);
    int*    rowptr = (int*)alloc(sizeof(int) * (N_NODES + 1));
    int*    bsum   = (int*)alloc(sizeof(int) * 64);
    int*    boff   = (int*)alloc(sizeof(int) * 64);
    int*    csr    = (int*)alloc(sizeof(int) * E_EDGES);
    __bf16* P1     = (__bf16*)alloc(sizeof(__bf16) * 256 * 128);
    __bf16* P2     = (__bf16*)alloc(sizeof(__bf16) * 256 * 128);
    __bf16* P3     = (__bf16*)alloc(sizeof(__bf16) * 256 * 128);
    __bf16* xb     = (__bf16*)alloc(sizeof(__bf16) * (size_t)N_NODES * 128);
    __bf16* aggb   = (__bf16*)alloc(sizeof(__bf16) * (size_t)N_NODES * 128);
    __bf16* h1b    = (__bf16*)alloc(sizeof(__bf16) * (size_t)N_NODES * 128);
    __bf16* h2b    = (__bf16*)alloc(sizeof(__bf16) * (size_t)N_NODES * 128);
    (void)ws_size; (void)in_sizes; (void)n_in; (void)out_size;

    hipMemsetAsync(deg, 0, sizeof(int) * N_NODES, stream);
    hipMemsetAsync(fil, 0, sizeof(int) * N_NODES, stream);

    const int nScanBlk = (N_NODES + 1023) / 1024;
    count_deg_k<<<(E_EDGES + 255) / 256, 256, 0, stream>>>(dstv, deg);
    scanA_k<<<nScanBlk, 1024, 0, stream>>>(deg, rowptr, bsum);
    scanB_k<<<1, 1, 0, stream>>>(bsum, boff, rowptr, nScanBlk);
    scanC_k<<<(N_NODES + 255) / 256, 256, 0, stream>>>(rowptr, boff);
    fill_csr_k<<<(E_EDGES + 255) / 256, 256, 0, stream>>>(srcv, dstv, rowptr, fil, csr);
    prep_wpack_k<<<(256 * 128 + 255) / 256, 256, 0, stream>>>(Wl1, Wr1, Wl2, Wr2, W3, P1, P2, P3);
    conv_x_k<<<(N_NODES * 128 / 4 + 255) / 256, 256, 0, stream>>>(x, xb);

    // layer 1
    aggregate_bf_k<<<(N_NODES + 15) / 16, 256, 0, stream>>>(xb, rowptr, csr, aggb);
    layer_mfma_k<<<(N_NODES + 127) / 128, 256, 0, stream>>>(aggb, xb, P1, b1, h1b);
    // layer 2
    aggregate_bf_k<<<(N_NODES + 15) / 16, 256, 0, stream>>>(h1b, rowptr, csr, aggb);
    layer_mfma_k<<<(N_NODES + 127) / 128, 256, 0, stream>>>(aggb, h1b, P2, b2, h2b);
    // pair scoring
    pair_mfma_k<<<(P_PAIRS + 127) / 128, 256, 0, stream>>>(h2b, prs, P3, b3, W4, b4, out);
}

// Round 3
// 257.993 us; speedup vs baseline: 2.2427x; 1.1924x over previous
//
#include <hip/hip_runtime.h>
#include <math.h>

#define N_NODES 50000
#define E_EDGES 500000
#define P_PAIRS 200000

typedef __bf16    bf16x8 __attribute__((ext_vector_type(8)));
typedef _Float16  f16x8  __attribute__((ext_vector_type(8)));
typedef float     f32x4  __attribute__((ext_vector_type(4)));

// ---------------- fused prologue: conv_x + count_deg + weight pack ----------------
// P1/P2 (layer weights, K=256,N=128): [kt(8)][nt(8)][lane(64)][j(8)]
//   n = nt*16+(lane&15), k = kt*32+(lane>>4)*8+j ; k<128 -> Wl[n][k], else Wr[n][k-128]
// P4 (pair weights, K=128,N=256):     [kt(4)][nt(16)][lane(64)][j(8)]
//   n'= nt*16+(lane&15), k = kt*32+(lane>>4)*8+j ; n'<128 -> W3[n'][k], else W3[n'-128][128+k]

#define CONV_BLKS 6250   // N_NODES*128/4/256
#define CNT_BLKS  1954   // ceil(E/256)
#define PREP_BLKS 128    // 32768/256

__global__ __launch_bounds__(256) void fused_pre_k(
        const float* __restrict__ x, __bf16* __restrict__ xb,
        const int* __restrict__ dst, int* __restrict__ deg,
        const float* __restrict__ Wl1, const float* __restrict__ Wr1,
        const float* __restrict__ Wl2, const float* __restrict__ Wr2,
        const float* __restrict__ W3,
        __bf16* __restrict__ P1, __bf16* __restrict__ P2, __bf16* __restrict__ P4) {
    int b = blockIdx.x, t = threadIdx.x;
    if (b < CONV_BLKS) {
        int i = b * 256 + t;                      // float4 index
        float4 v = ((const float4*)x)[i];
        __bf16* o = xb + (size_t)i * 4;
        o[0] = (__bf16)v.x; o[1] = (__bf16)v.y; o[2] = (__bf16)v.z; o[3] = (__bf16)v.w;
    } else if (b < CONV_BLKS + CNT_BLKS) {
        int e = (b - CONV_BLKS) * 256 + t;
        if (e < E_EDGES) atomicAdd(&deg[dst[e]], 1);
    } else {
        int i = (b - CONV_BLKS - CNT_BLKS) * 256 + t;   // 0..32767
        int lane = (i >> 3) & 63;
        int j = i & 7;
        int kq = (lane >> 4) * 8 + j;
        // P1/P2: K=256 layout
        {
            int kt = i >> 12, nt = (i >> 9) & 7;
            int n = nt * 16 + (lane & 15);
            int k = kt * 32 + kq;
            P1[i] = (__bf16)((k < 128) ? Wl1[n * 128 + k] : Wr1[n * 128 + (k - 128)]);
            P2[i] = (__bf16)((k < 128) ? Wl2[n * 128 + k] : Wr2[n * 128 + (k - 128)]);
        }
        // P4: K=128, N=256 layout
        {
            int kt = i >> 13, nt = (i >> 9) & 15;
            int n = nt * 16 + (lane & 15);
            int k = kt * 32 + kq;
            P4[i] = (__bf16)((n < 128) ? W3[n * 256 + k] : W3[(n - 128) * 256 + 128 + k]);
        }
    }
}

// ---------------- CSR build ----------------

__global__ __launch_bounds__(1024) void scanA_k(const int* __restrict__ deg,
                                                int* __restrict__ rowptr,
                                                int* __restrict__ blockSums) {
    __shared__ int buf[1024];
    int t = threadIdx.x;
    int i = blockIdx.x * 1024 + t;
    int v = (i < N_NODES) ? deg[i] : 0;
    buf[t] = v;
    __syncthreads();
    for (int off = 1; off < 1024; off <<= 1) {
        int xv = (t >= off) ? buf[t - off] : 0;
        __syncthreads();
        buf[t] += xv;
        __syncthreads();
    }
    if (i < N_NODES) rowptr[i] = buf[t] - v;
    if (t == 1023) blockSums[blockIdx.x] = buf[1023];
}

__global__ void scanBC_k(int* __restrict__ rowptr, const int* __restrict__ blockSums,
                         int nblk) {
    int i = blockIdx.x * blockDim.x + threadIdx.x;
    if (i <= N_NODES) {
        int blk = (i == N_NODES) ? nblk : (i >> 10);
        int run = 0;
        for (int b = 0; b < blk; ++b) run += blockSums[b];
        if (i == N_NODES) rowptr[i] = run;
        else rowptr[i] += run;
    }
}

__global__ void fill_csr_k(const int* __restrict__ src, const int* __restrict__ dst,
                           const int* __restrict__ rowptr, int* __restrict__ fil,
                           int* __restrict__ csr) {
    int e = blockIdx.x * blockDim.x + threadIdx.x;
    if (e < E_EDGES) {
        int d = dst[e];
        int pos = rowptr[d] + atomicAdd(&fil[d], 1);
        csr[pos] = src[e];
    }
}

// ---------------- segment-mean aggregation (bf16), 4-wide unrolled ----------------

__global__ __launch_bounds__(256) void aggregate_bf_k(const __bf16* __restrict__ feat,
                                                      const int* __restrict__ rowptr,
                                                      const int* __restrict__ csr,
                                                      __bf16* __restrict__ agg) {
    int n = blockIdx.x * 16 + (threadIdx.x >> 4);
    if (n >= N_NODES) return;
    int l = threadIdx.x & 15;
    int beg = rowptr[n], end = rowptr[n + 1];
    float s[8];
    #pragma unroll
    for (int e = 0; e < 8; ++e) s[e] = 0.f;
    int j = beg;
    for (; j + 4 <= end; j += 4) {
        int sn0 = csr[j], sn1 = csr[j + 1], sn2 = csr[j + 2], sn3 = csr[j + 3];
        bf16x8 v0 = *(const bf16x8*)(feat + (size_t)sn0 * 128 + l * 8);
        bf16x8 v1 = *(const bf16x8*)(feat + (size_t)sn1 * 128 + l * 8);
        bf16x8 v2 = *(const bf16x8*)(feat + (size_t)sn2 * 128 + l * 8);
        bf16x8 v3 = *(const bf16x8*)(feat + (size_t)sn3 * 128 + l * 8);
        #pragma unroll
        for (int e = 0; e < 8; ++e)
            s[e] += (float)v0[e] + (float)v1[e] + (float)v2[e] + (float)v3[e];
    }
    for (; j < end; ++j) {
        int sn = csr[j];
        bf16x8 v = *(const bf16x8*)(feat + (size_t)sn * 128 + l * 8);
        #pragma unroll
        for (int e = 0; e < 8; ++e) s[e] += (float)v[e];
    }
    float inv = 1.0f / fmaxf((float)(end - beg), 1.0f);
    bf16x8 o;
    #pragma unroll
    for (int e = 0; e < 8; ++e) o[e] = (__bf16)(s[e] * inv);
    *(bf16x8*)(agg + (size_t)n * 128 + l * 8) = o;
}

// ---------------- SAGE layer: out = relu([agg|feat] @ B + bias), 16 rows/wave ----------------

__global__ __launch_bounds__(256) void layer_mfma_k(const __bf16* __restrict__ agg,
                                                    const __bf16* __restrict__ feat,
                                                    const __bf16* __restrict__ wpack,
                                                    const float* __restrict__ bias,
                                                    __bf16* __restrict__ out) {
    int wave = threadIdx.x >> 6;
    int lane = threadIdx.x & 63;
    int m = lane & 15, quad = lane >> 4;
    int rbase = blockIdx.x * 64 + wave * 16;
    int r0 = rbase + m; if (r0 > N_NODES - 1) r0 = N_NODES - 1;

    f32x4 acc[8];
    #pragma unroll
    for (int nt = 0; nt < 8; ++nt) acc[nt] = (f32x4)0.f;

    #pragma unroll
    for (int kt = 0; kt < 8; ++kt) {
        const __bf16* src = (kt < 4) ? agg : feat;
        int ko = (kt & 3) * 32 + quad * 8;
        bf16x8 a0 = *(const bf16x8*)(src + (size_t)r0 * 128 + ko);
        const __bf16* wb = wpack + (size_t)kt * 4096 + lane * 8;
        #pragma unroll
        for (int nt = 0; nt < 8; ++nt) {
            bf16x8 b = *(const bf16x8*)(wb + nt * 512);
            acc[nt] = __builtin_amdgcn_mfma_f32_16x16x32_bf16(a0, b, acc[nt], 0, 0, 0);
        }
    }

    #pragma unroll
    for (int r = 0; r < 4; ++r) {
        int row = rbase + quad * 4 + r;
        if (row < N_NODES) {
            #pragma unroll
            for (int nt = 0; nt < 8; ++nt) {
                float v = acc[nt][r] + bias[nt * 16 + m];
                out[(size_t)row * 128 + nt * 16 + m] = (__bf16)fmaxf(v, 0.f);
            }
        }
    }
}

// ---------------- UV = h2 @ [W3a|W3b]^T  (fp16 out, no bias) ----------------

__global__ __launch_bounds__(256) void uv_mfma_k(const __bf16* __restrict__ h2,
                                                 const __bf16* __restrict__ wpack,
                                                 _Float16* __restrict__ UV) {
    int wave = threadIdx.x >> 6;
    int lane = threadIdx.x & 63;
    int m = lane & 15, quad = lane >> 4;
    int rbase = blockIdx.x * 64 + wave * 16;
    int r0 = rbase + m; if (r0 > N_NODES - 1) r0 = N_NODES - 1;

    f32x4 acc[16];
    #pragma unroll
    for (int nt = 0; nt < 16; ++nt) acc[nt] = (f32x4)0.f;

    #pragma unroll
    for (int kt = 0; kt < 4; ++kt) {
        int ko = kt * 32 + quad * 8;
        bf16x8 a0 = *(const bf16x8*)(h2 + (size_t)r0 * 128 + ko);
        const __bf16* wb = wpack + (size_t)kt * 8192 + lane * 8;
        #pragma unroll
        for (int nt = 0; nt < 16; ++nt) {
            bf16x8 b = *(const bf16x8*)(wb + nt * 512);
            acc[nt] = __builtin_amdgcn_mfma_f32_16x16x32_bf16(a0, b, acc[nt], 0, 0, 0);
        }
    }

    #pragma unroll
    for (int r = 0; r < 4; ++r) {
        int row = rbase + quad * 4 + r;
        if (row < N_NODES) {
            #pragma unroll
            for (int nt = 0; nt < 16; ++nt)
                UV[(size_t)row * 256 + nt * 16 + m] = (_Float16)acc[nt][r];
        }
    }
}

// ---------------- pair epilogue: sigmoid(relu(U[a]+V[b]+b3) . W4 + b4) ----------------
// 16 lanes per pair, 4 pairs per group for MLP; 64 pairs per 256-thread block.

__global__ __launch_bounds__(256) void pair_ep_k(const _Float16* __restrict__ UV,
                                                 const int* __restrict__ pairs,
                                                 const float* __restrict__ b3,
                                                 const float* __restrict__ W4,
                                                 const float* __restrict__ b4,
                                                 float* __restrict__ out) {
    int t = threadIdx.x;
    int g = t >> 4, l = t & 15;
    int base = blockIdx.x * 64;

    float4 b3a = *(const float4*)(b3 + l * 8);
    float4 b3b = *(const float4*)(b3 + l * 8 + 4);
    float4 w4a = *(const float4*)(W4 + l * 8);
    float4 w4b = *(const float4*)(W4 + l * 8 + 4);
    float bb[8] = {b3a.x, b3a.y, b3a.z, b3a.w, b3b.x, b3b.y, b3b.z, b3b.w};
    float ww[8] = {w4a.x, w4a.y, w4a.z, w4a.w, w4b.x, w4b.y, w4b.z, w4b.w};
    float b4s = b4[0];

    int2 pr[4];
    #pragma unroll
    for (int i = 0; i < 4; ++i) pr[i] = ((const int2*)pairs)[base + i * 16 + g];

    f16x8 ua[4], vb[4];
    #pragma unroll
    for (int i = 0; i < 4; ++i) {
        ua[i] = *(const f16x8*)(UV + (size_t)pr[i].x * 256 + l * 8);
        vb[i] = *(const f16x8*)(UV + (size_t)pr[i].y * 256 + 128 + l * 8);
    }

    #pragma unroll
    for (int i = 0; i < 4; ++i) {
        float p = 0.f;
        #pragma unroll
        for (int e = 0; e < 8; ++e)
            p += fmaxf((float)ua[i][e] + (float)vb[i][e] + bb[e], 0.f) * ww[e];
        #pragma unroll
        for (int s = 1; s < 16; s <<= 1) p += __shfl_xor(p, s, 64);
        if (l == 0)
            out[base + i * 16 + g] = 1.0f / (1.0f + expf(-(p + b4s)));
    }
}

// ---------------- launch ----------------

extern "C" void kernel_launch(void* const* d_in, const int* in_sizes, int n_in,
                              void* d_out, int out_size, void* d_ws, size_t ws_size,
                              hipStream_t stream) {
    const float* x   = (const float*)d_in[0];
    const int*   ei  = (const int*)d_in[1];
    const int*   prs = (const int*)d_in[2];
    const float* Wl1 = (const float*)d_in[3];
    const float* Wr1 = (const float*)d_in[4];
    const float* b1  = (const float*)d_in[5];
    const float* Wl2 = (const float*)d_in[6];
    const float* Wr2 = (const float*)d_in[7];
    const float* b2  = (const float*)d_in[8];
    const float* W3  = (const float*)d_in[9];
    const float* b3  = (const float*)d_in[10];
    const float* W4  = (const float*)d_in[11];
    const float* b4  = (const float*)d_in[12];
    float* out = (float*)d_out;

    const int* srcv = ei;
    const int* dstv = ei + E_EDGES;

    char* ws = (char*)d_ws;
    size_t off = 0;
    auto alloc = [&](size_t bytes) -> void* {
        void* p = ws + off;
        off = (off + bytes + 255) & ~(size_t)255;
        return p;
    };
    int*      deg    = (int*)alloc(sizeof(int) * N_NODES);
    int*      fil    = (int*)alloc(sizeof(int) * N_NODES);
    int*      rowptr = (int*)alloc(sizeof(int) * (N_NODES + 1));
    int*      bsum   = (int*)alloc(sizeof(int) * 64);
    int*      csr    = (int*)alloc(sizeof(int) * E_EDGES);
    __bf16*   P1     = (__bf16*)alloc(sizeof(__bf16) * 32768);
    __bf16*   P2     = (__bf16*)alloc(sizeof(__bf16) * 32768);
    __bf16*   P4     = (__bf16*)alloc(sizeof(__bf16) * 32768);
    __bf16*   xb     = (__bf16*)alloc(sizeof(__bf16) * (size_t)N_NODES * 128);
    __bf16*   aggb   = (__bf16*)alloc(sizeof(__bf16) * (size_t)N_NODES * 128);
    __bf16*   h1b    = (__bf16*)alloc(sizeof(__bf16) * (size_t)N_NODES * 128);
    __bf16*   h2b    = (__bf16*)alloc(sizeof(__bf16) * (size_t)N_NODES * 128);
    _Float16* UV     = (_Float16*)alloc(sizeof(_Float16) * (size_t)N_NODES * 256);
    (void)ws_size; (void)in_sizes; (void)n_in; (void)out_size;

    hipMemsetAsync(deg, 0, sizeof(int) * N_NODES, stream);
    hipMemsetAsync(fil, 0, sizeof(int) * N_NODES, stream);

    const int nScanBlk = (N_NODES + 1023) / 1024;
    fused_pre_k<<<CONV_BLKS + CNT_BLKS + PREP_BLKS, 256, 0, stream>>>(
        x, xb, dstv, deg, Wl1, Wr1, Wl2, Wr2, W3, P1, P2, P4);
    scanA_k<<<nScanBlk, 1024, 0, stream>>>(deg, rowptr, bsum);
    scanBC_k<<<(N_NODES + 256) / 256, 256, 0, stream>>>(rowptr, bsum, nScanBlk);
    fill_csr_k<<<(E_EDGES + 255) / 256, 256, 0, stream>>>(srcv, dstv, rowptr, fil, csr);

    // layer 1
    aggregate_bf_k<<<(N_NODES + 15) / 16, 256, 0, stream>>>(xb, rowptr, csr, aggb);
    layer_mfma_k<<<(N_NODES + 63) / 64, 256, 0, stream>>>(aggb, xb, P1, b1, h1b);
    // layer 2
    aggregate_bf_k<<<(N_NODES + 15) / 16, 256, 0, stream>>>(h1b, rowptr, csr, aggb);
    layer_mfma_k<<<(N_NODES + 63) / 64, 256, 0, stream>>>(aggb, h1b, P2, b2, h2b);
    // pair scoring: UV precompute + epilogue
    uv_mfma_k<<<(N_NODES + 63) / 64, 256, 0, stream>>>(h2b, P4, UV);
    pair_ep_k<<<P_PAIRS / 64, 256, 0, stream>>>(UV, prs, b3, W4, b4, out);
}